// Round 2
// baseline (450.277 us; speedup 1.0000x reference)
//
#include <hip/hip_runtime.h>
#include <math.h>

typedef unsigned short u16;
typedef __attribute__((ext_vector_type(8))) short short8;   // 8 bf16 = 4 VGPRs (MFMA A/B frag)
typedef __attribute__((ext_vector_type(4))) float f32x4;    // MFMA C/D frag / float4 load

__device__ __forceinline__ u16 f2b(float f) {   // f32 -> bf16, round-to-nearest-even
    unsigned u = __float_as_uint(f);
    u += 0x7fffu + ((u >> 16) & 1u);
    return (u16)(u >> 16);
}

// convert 8 consecutive f32 (16B-aligned x2) -> one bf16 A/B fragment
__device__ __forceinline__ short8 cvt8(const f32x4* __restrict__ p) {
    f32x4 a = p[0], b = p[1];
    short8 r;
    r[0] = (short)f2b(a[0]); r[1] = (short)f2b(a[1]);
    r[2] = (short)f2b(a[2]); r[3] = (short)f2b(a[3]);
    r[4] = (short)f2b(b[0]); r[5] = (short)f2b(b[1]);
    r[6] = (short)f2b(b[2]); r[7] = (short)f2b(b[3]);
    return r;
}

// ---- prep (f32 in, bf16 out):
//   WaT[c][k] = bf16(Wa[k][c])
//   WpT[c][k] = bf16(Wl[k][c] + Wl[134+k][c])   (p/q blocks of Wl cancel in me2[:E]+me2[E:])
__global__ void k_prep(const float* __restrict__ Wa, const float* __restrict__ Wl,
                       u16* __restrict__ WpT, u16* __restrict__ WaT)
{
    const int c = blockIdx.x;    // 0..127 (output col)
    const int k = threadIdx.x;   // 0..127 (input dim)
    WaT[c * 128 + k] = f2b(Wa[k * 128 + c]);
    WpT[c * 128 + k] = f2b(Wl[k * 128 + c] + Wl[(134 + k) * 128 + c]);
}

__global__ void k_mark0(unsigned char* __restrict__ mark, int NV)
{
    int i = blockIdx.x * 256 + threadIdx.x;
    if (i < NV) mark[i] = 0;
}

__global__ void k_mark(const int* __restrict__ eu, const int* __restrict__ ev,
                       unsigned char* __restrict__ mark, int NE)
{
    int i = blockIdx.x * 256 + threadIdx.x;
    if (i < NE) { mark[eu[i]] = 1; mark[ev[i]] = 1; }
}

// ---- mv[n][c] = mark[n] ? elu(lrelu(hv[n]@Wa + ba)) : 0
// (softmax collapses: attend depends only on the destination vertex, sum(align)=1)
__global__ __launch_bounds__(256, 2) void k_mv(
    const float* __restrict__ hv, const u16* __restrict__ WT, const float* __restrict__ ba,
    const unsigned char* __restrict__ mark, float* __restrict__ out, int NV)
{
    const int lane = threadIdx.x & 63;
    const int wv   = threadIdx.x >> 6;
    const int m = lane & 15, q = lane >> 4;
    const int n0 = blockIdx.x * 64 + wv * 16;   // this wave's 16 rows

    int nl = n0 + m; if (nl >= NV) nl = NV - 1;   // clamp for tail loads

    short8 a[4];
    {
        const f32x4* ap = (const f32x4*)(hv + (size_t)nl * 128 + q * 8);
        #pragma unroll
        for (int ks = 0; ks < 4; ++ks) a[ks] = cvt8(ap + ks * 8);   // +32 floats per k-step
    }

    f32x4 acc[8];
    #pragma unroll
    for (int t = 0; t < 8; ++t) acc[t] = (f32x4){0.f, 0.f, 0.f, 0.f};

    #pragma unroll
    for (int ks = 0; ks < 4; ++ks) {
        #pragma unroll
        for (int t = 0; t < 8; ++t) {
            short8 b = *(const short8*)(WT + (size_t)(t * 16 + m) * 128 + ks * 32 + q * 8);
            acc[t] = __builtin_amdgcn_mfma_f32_16x16x32_bf16(a[ks], b, acc[t], 0, 0, 0);
        }
    }

    #pragma unroll
    for (int t = 0; t < 8; ++t) {
        const int col  = t * 16 + m;
        const float bias = ba[col];
        #pragma unroll
        for (int i = 0; i < 4; ++i) {
            const int row = n0 + q * 4 + i;
            if (row < NV) {
                float z = acc[t][i] + bias;
                float y = (z > 0.f) ? z : 0.01f * z;          // leaky_relu
                float r = (y > 0.f) ? y : (__expf(y) - 1.f);  // elu
                if (mark[row] == 0) r = 0.f;                  // empty segment -> elu(0)=0
                out[(size_t)row * 128 + col] = r;
            }
        }
    }
}

// ---- me[i][c] = lrelu((hv[u]+hv[v]) @ W' + 2*bl) ; u/v fed as two MFMAs (no pre-sum rounding)
__global__ __launch_bounds__(256, 2) void k_me(
    const float* __restrict__ hv, const int* __restrict__ eu, const int* __restrict__ ev,
    const u16* __restrict__ WT, const float* __restrict__ bl, float* __restrict__ out, int NE)
{
    const int lane = threadIdx.x & 63;
    const int wv   = threadIdx.x >> 6;
    const int m = lane & 15, q = lane >> 4;
    const int e0 = blockIdx.x * 64 + wv * 16;   // this wave's 16 edges

    int e = e0 + m; if (e >= NE) e = NE - 1;    // clamp for tail loads
    const int iu = eu[e];
    const int iv = ev[e];

    short8 au[4], av[4];
    {
        const f32x4* up = (const f32x4*)(hv + (size_t)iu * 128 + q * 8);
        const f32x4* vp = (const f32x4*)(hv + (size_t)iv * 128 + q * 8);
        #pragma unroll
        for (int ks = 0; ks < 4; ++ks) { au[ks] = cvt8(up + ks * 8); av[ks] = cvt8(vp + ks * 8); }
    }

    f32x4 acc[8];
    #pragma unroll
    for (int t = 0; t < 8; ++t) acc[t] = (f32x4){0.f, 0.f, 0.f, 0.f};

    #pragma unroll
    for (int ks = 0; ks < 4; ++ks) {
        short8 b[8];
        #pragma unroll
        for (int t = 0; t < 8; ++t)
            b[t] = *(const short8*)(WT + (size_t)(t * 16 + m) * 128 + ks * 32 + q * 8);
        #pragma unroll
        for (int t = 0; t < 8; ++t)
            acc[t] = __builtin_amdgcn_mfma_f32_16x16x32_bf16(au[ks], b[t], acc[t], 0, 0, 0);
        #pragma unroll
        for (int t = 0; t < 8; ++t)
            acc[t] = __builtin_amdgcn_mfma_f32_16x16x32_bf16(av[ks], b[t], acc[t], 0, 0, 0);
    }

    #pragma unroll
    for (int t = 0; t < 8; ++t) {
        const int col  = t * 16 + m;
        const float bias = 2.0f * bl[col];
        #pragma unroll
        for (int i = 0; i < 4; ++i) {
            const int row = e0 + q * 4 + i;
            if (row < NE) {
                float x = acc[t][i] + bias;
                x = (x > 0.f) ? x : 0.01f * x;   // leaky_relu
                out[(size_t)row * 128 + col] = x;
            }
        }
    }
}

extern "C" void kernel_launch(void* const* d_in, const int* in_sizes, int n_in,
                              void* d_out, int out_size, void* d_ws, size_t ws_size,
                              hipStream_t stream)
{
    // setup_inputs order: 0 hv,1 he,2 p,3 q,4 edge_u,5 edge_v,6 Wa,7 ba,8 Wal,9 bal,10 Wl,11 bl
    const float* hv = (const float*)d_in[0];
    const int*   eu = (const int*)d_in[4];
    const int*   ev = (const int*)d_in[5];
    const float* Wa = (const float*)d_in[6];
    const float* ba = (const float*)d_in[7];
    const float* Wl = (const float*)d_in[10];
    const float* bl = (const float*)d_in[11];

    const int NV = in_sizes[0] / 128;   // 50000
    const int NE = in_sizes[4];         // 400000

    // workspace layout: W'T bf16 (32KB) | WaT bf16 (32KB) | mark (NV bytes) -> ~115KB total
    u16* WpT = (u16*)d_ws;
    u16* WaT = WpT + 128 * 128;
    unsigned char* mark = (unsigned char*)(WaT + 128 * 128);

    float* mv_out = (float*)d_out;
    float* me_out = mv_out + (size_t)NV * 128;

    k_prep <<<128, 128, 0, stream>>>(Wa, Wl, WpT, WaT);
    k_mark0<<<(NV + 255) / 256, 256, 0, stream>>>(mark, NV);
    k_mark <<<(NE + 255) / 256, 256, 0, stream>>>(eu, ev, mark, NE);
    k_mv   <<<(NV + 63) / 64, 256, 0, stream>>>(hv, WaT, ba, mark, mv_out, NV);
    k_me   <<<(NE + 63) / 64, 256, 0, stream>>>(hv, eu, ev, WpT, bl, me_out, NE);
}

// Round 3
// 428.805 us; speedup vs baseline: 1.0501x; 1.0501x over previous
//
#include <hip/hip_runtime.h>
#include <math.h>

typedef unsigned short u16;
typedef __attribute__((ext_vector_type(8))) short short8;   // 8 bf16 = one MFMA A/B frag
typedef __attribute__((ext_vector_type(4))) float f32x4;

__device__ __forceinline__ u16 f2b(float f) {   // f32 -> bf16 RNE
    unsigned u = __float_as_uint(f);
    u += 0x7fffu + ((u >> 16) & 1u);
    return (u16)(u >> 16);
}

__device__ __forceinline__ short8 cvt8(const f32x4* __restrict__ p) {
    f32x4 a = p[0], b = p[1];
    short8 r;
    r[0] = (short)f2b(a[0]); r[1] = (short)f2b(a[1]);
    r[2] = (short)f2b(a[2]); r[3] = (short)f2b(a[3]);
    r[4] = (short)f2b(b[0]); r[5] = (short)f2b(b[1]);
    r[6] = (short)f2b(b[2]); r[7] = (short)f2b(b[3]);
    return r;
}

// ---- prep: hvb = bf16(hv) (NVx128), mark = 0, WaT[c][k]=bf16(Wa[k][c]),
//      WpT[c][k]=bf16(Wl[k][c]+Wl[134+k][c])  (p/q blocks of Wl cancel in me2[:E]+me2[E:])
__global__ __launch_bounds__(256) void k_prep(
    const float* __restrict__ hv, const float* __restrict__ Wa, const float* __restrict__ Wl,
    u16* __restrict__ hvb, u16* __restrict__ WpT, u16* __restrict__ WaT,
    unsigned char* __restrict__ mark, int NV, int nbHV)
{
    if ((int)blockIdx.x < nbHV) {
        size_t base = (size_t)blockIdx.x * 2048 + (size_t)threadIdx.x * 8;
        if (base + 8 <= (size_t)NV * 128) {
            short8 r = cvt8((const f32x4*)(hv + base));
            *(short8*)(hvb + base) = r;
        }
        int r0 = (int)blockIdx.x * 16 + (int)threadIdx.x;
        if (threadIdx.x < 16 && r0 < NV) mark[r0] = 0;
    } else {
        int c = ((int)blockIdx.x - nbHV) * 2 + ((int)threadIdx.x >> 7);
        int k = threadIdx.x & 127;
        WaT[c * 128 + k] = f2b(Wa[k * 128 + c]);
        WpT[c * 128 + k] = f2b(Wl[k * 128 + c] + Wl[(134 + k) * 128 + c]);
    }
}

__global__ void k_mark(const int* __restrict__ eu, const int* __restrict__ ev,
                       unsigned char* __restrict__ mark, int NE)
{
    int i = blockIdx.x * 256 + threadIdx.x;
    if (i < NE) { mark[eu[i]] = 1; mark[ev[i]] = 1; }
}

// ---- fused main kernel.
// blocks [0,nbE):  me[i][c] = lrelu((hv[u]+hv[v]) @ W' + 2*bl)   (u,v fed as 2 MFMAs)
// blocks [nbE,..): mv[n][c] = mark[n] ? elu(lrelu(hv[n]@Wa + ba)) : 0
//                  (softmax is dead code: attend depends only on dest vertex, sum(align)=1)
__global__ __launch_bounds__(256) void k_main(
    const u16* __restrict__ hvb, const float* __restrict__ hv,
    const int* __restrict__ eu, const int* __restrict__ ev,
    const u16* __restrict__ WpT, const u16* __restrict__ WaT,
    const float* __restrict__ bl, const float* __restrict__ ba,
    const unsigned char* __restrict__ mark,
    float* __restrict__ mv_out, float* __restrict__ me_out,
    int NE, int NV, int nbE)
{
    const int lane = threadIdx.x & 63;
    const int wv   = threadIdx.x >> 6;
    const int m = lane & 15, q = lane >> 4;

    if ((int)blockIdx.x < nbE) {
        // ---------------- edge part ----------------
        const int e0 = blockIdx.x * 64 + wv * 16;
        int e = e0 + m; if (e >= NE) e = NE - 1;
        const int iu = eu[e];
        const int iv = ev[e];

        short8 au[4], av[4];
        {
            const short8* up = (const short8*)(hvb + (size_t)iu * 128 + q * 8);
            const short8* vp = (const short8*)(hvb + (size_t)iv * 128 + q * 8);
            #pragma unroll
            for (int ks = 0; ks < 4; ++ks) { au[ks] = up[ks * 4]; av[ks] = vp[ks * 4]; }
        }

        f32x4 acc[8];
        #pragma unroll
        for (int t = 0; t < 8; ++t) acc[t] = (f32x4){0.f, 0.f, 0.f, 0.f};

        #pragma unroll
        for (int ks = 0; ks < 4; ++ks) {
            short8 b[8];
            #pragma unroll
            for (int t = 0; t < 8; ++t)
                b[t] = *(const short8*)(WpT + (size_t)(t * 16 + m) * 128 + ks * 32 + q * 8);
            #pragma unroll
            for (int t = 0; t < 8; ++t)
                acc[t] = __builtin_amdgcn_mfma_f32_16x16x32_bf16(au[ks], b[t], acc[t], 0, 0, 0);
            #pragma unroll
            for (int t = 0; t < 8; ++t)
                acc[t] = __builtin_amdgcn_mfma_f32_16x16x32_bf16(av[ks], b[t], acc[t], 0, 0, 0);
        }

        #pragma unroll
        for (int t = 0; t < 8; ++t) {
            const int col  = t * 16 + m;
            const float bias = 2.0f * bl[col];
            #pragma unroll
            for (int i = 0; i < 4; ++i) {
                const int row = e0 + q * 4 + i;
                if (row < NE) {
                    float x = acc[t][i] + bias;
                    x = (x > 0.f) ? x : 0.01f * x;   // leaky_relu
                    __builtin_nontemporal_store(x, &me_out[(size_t)row * 128 + col]);
                }
            }
        }
    } else {
        // ---------------- vertex part ----------------
        const int vb = (int)blockIdx.x - nbE;
        const int n0 = vb * 64 + wv * 16;
        int nl = n0 + m; if (nl >= NV) nl = NV - 1;

        short8 a[4];
        {
            const f32x4* ap = (const f32x4*)(hv + (size_t)nl * 128 + q * 8);
            #pragma unroll
            for (int ks = 0; ks < 4; ++ks) a[ks] = cvt8(ap + ks * 8);
        }

        f32x4 acc[8];
        #pragma unroll
        for (int t = 0; t < 8; ++t) acc[t] = (f32x4){0.f, 0.f, 0.f, 0.f};

        #pragma unroll
        for (int ks = 0; ks < 4; ++ks) {
            #pragma unroll
            for (int t = 0; t < 8; ++t) {
                short8 b = *(const short8*)(WaT + (size_t)(t * 16 + m) * 128 + ks * 32 + q * 8);
                acc[t] = __builtin_amdgcn_mfma_f32_16x16x32_bf16(a[ks], b, acc[t], 0, 0, 0);
            }
        }

        #pragma unroll
        for (int t = 0; t < 8; ++t) {
            const int col  = t * 16 + m;
            const float bias = ba[col];
            #pragma unroll
            for (int i = 0; i < 4; ++i) {
                const int row = n0 + q * 4 + i;
                if (row < NV) {
                    float z = acc[t][i] + bias;
                    float y = (z > 0.f) ? z : 0.01f * z;          // leaky_relu
                    float r = (y > 0.f) ? y : (__expf(y) - 1.f);  // elu
                    if (mark[row] == 0) r = 0.f;                  // empty segment -> elu(0)=0
                    __builtin_nontemporal_store(r, &mv_out[(size_t)row * 128 + col]);
                }
            }
        }
    }
}

extern "C" void kernel_launch(void* const* d_in, const int* in_sizes, int n_in,
                              void* d_out, int out_size, void* d_ws, size_t ws_size,
                              hipStream_t stream)
{
    // inputs: 0 hv,1 he,2 p,3 q,4 edge_u,5 edge_v,6 Wa,7 ba,8 Wal,9 bal,10 Wl,11 bl
    const float* hv = (const float*)d_in[0];
    const int*   eu = (const int*)d_in[4];
    const int*   ev = (const int*)d_in[5];
    const float* Wa = (const float*)d_in[6];
    const float* ba = (const float*)d_in[7];
    const float* Wl = (const float*)d_in[10];
    const float* bl = (const float*)d_in[11];

    const int NV = in_sizes[0] / 128;   // 50000
    const int NE = in_sizes[4];         // 400000

    float* mv_out = (float*)d_out;
    float* me_out = mv_out + (size_t)NV * 128;

    const int nbHV = (NV * 128 + 2047) / 2048;          // hv->bf16 blocks (2048 elems each)
    const int nbE  = (NE + 63) / 64;
    const int nbV  = (NV + 63) / 64;

    const size_t hvb_bytes = (size_t)NV * 128 * 2;      // 12.8 MB
    const size_t need_ws   = hvb_bytes + 128 * 128 * 2 * 2 + (size_t)NV;

    if (ws_size >= need_ws) {
        // hvb fits in workspace: fully fused path (3 launches, mv overlaps me)
        u16* hvb = (u16*)d_ws;
        u16* WpT = hvb + (size_t)NV * 128;
        u16* WaT = WpT + 128 * 128;
        unsigned char* mark = (unsigned char*)(WaT + 128 * 128);

        k_prep<<<nbHV + 64, 256, 0, stream>>>(hv, Wa, Wl, hvb, WpT, WaT, mark, NV, nbHV);
        k_mark<<<(NE + 255) / 256, 256, 0, stream>>>(eu, ev, mark, NE);
        k_main<<<nbE + nbV, 256, 0, stream>>>(hvb, hv, eu, ev, WpT, WaT, bl, ba, mark,
                                              mv_out, me_out, NE, NV, nbE);
    } else {
        // fallback: stage hvb in the (not yet written) mv region of d_out; serialize
        // edge pass (reads hvb) before vertex pass (overwrites mv region).
        u16* hvb = (u16*)mv_out;                         // 12.8 MB <= 25.6 MB region
        u16* WpT = (u16*)d_ws;
        u16* WaT = WpT + 128 * 128;
        unsigned char* mark = (unsigned char*)(WaT + 128 * 128);

        k_prep<<<nbHV + 64, 256, 0, stream>>>(hv, Wa, Wl, hvb, WpT, WaT, mark, NV, nbHV);
        k_mark<<<(NE + 255) / 256, 256, 0, stream>>>(eu, ev, mark, NE);
        k_main<<<nbE, 256, 0, stream>>>(hvb, hv, eu, ev, WpT, WaT, bl, ba, mark,
                                        mv_out, me_out, NE, NV, nbE);      // edges only
        k_main<<<nbV, 256, 0, stream>>>(hvb, hv, eu, ev, WpT, WaT, bl, ba, mark,
                                        mv_out, me_out, NE, NV, 0);        // vertices only
    }
}